// Round 2
// baseline (440.022 us; speedup 1.0000x reference)
//
#include <hip/hip_runtime.h>
#include <hip/hip_bf16.h>
#include <stdint.h>

#define NNODES 50000
#define NEDGES 800000
#define CH     256
#define NCLS   64

typedef __attribute__((ext_vector_type(8))) short  short8;
typedef __attribute__((ext_vector_type(4))) float  floatx4;

__device__ __forceinline__ float bf2f(unsigned short u) {
    union { unsigned int i; float f; } v; v.i = ((unsigned int)u) << 16; return v.f;
}
__device__ __forceinline__ unsigned short f2bf(float f) {
    union { float f; unsigned int i; } v; v.f = f;
    unsigned int x = v.i;
    return (unsigned short)((x + 0x7fffu + ((x >> 16) & 1u)) >> 16);  // RNE
}

// ---------------- fused setup: zero deg + transpose-convert all 3 weights ----------------
__global__ void k_setup(const float* __restrict__ W0, const float* __restrict__ W1,
                        const float* __restrict__ Wl,
                        unsigned short* __restrict__ w0t, unsigned short* __restrict__ w1t,
                        unsigned short* __restrict__ wlt, int* __restrict__ deg) {
    int i = blockIdx.x * 256 + threadIdx.x;
    if (i < 65536) {
        int r = i >> 8, c = i & 255;
        w0t[c * 256 + r] = f2bf(W0[i]);
    } else if (i < 131072) {
        int j = i - 65536;
        int r = j >> 8, c = j & 255;
        w1t[c * 256 + r] = f2bf(W1[j]);
    } else if (i < 147456) {
        int j = i - 131072;
        int r = j >> 6, c = j & 63;       // Wl is [256,64]
        wlt[c * 256 + r] = f2bf(Wl[j]);
    } else if (i < 147456 + NNODES) {
        deg[i - 147456] = 0;
    }
}

__global__ void k_hist(const int* __restrict__ dst, int* __restrict__ deg) {
    int e = blockIdx.x * 256 + threadIdx.x;
    if (e < NEDGES) {
        int d = dst[e];
        if ((unsigned)d < NNODES) atomicAdd(&deg[d], 1);
    }
}

__global__ void k_scan1(const int* __restrict__ in, int* __restrict__ out,
                        int* __restrict__ part, int n) {
    __shared__ int sm[256];
    int i = blockIdx.x * 256 + threadIdx.x;
    int v = (i < n) ? in[i] : 0;
    sm[threadIdx.x] = v;
    __syncthreads();
    for (int off = 1; off < 256; off <<= 1) {
        int t = (threadIdx.x >= (unsigned)off) ? sm[threadIdx.x - off] : 0;
        __syncthreads();
        sm[threadIdx.x] += t;
        __syncthreads();
    }
    if (i < n) out[i] = sm[threadIdx.x];
    if (threadIdx.x == 255) part[blockIdx.x] = sm[255];
}

__global__ void k_scan3(const int* __restrict__ scn, const int* __restrict__ deg,
                        const int* __restrict__ part, int* __restrict__ offs,
                        int* __restrict__ cursor, int n) {
    int i = blockIdx.x * 256 + threadIdx.x;
    if (i < n) {
        int add = (blockIdx.x > 0) ? part[blockIdx.x - 1] : 0;
        int o = scn[i] - deg[i] + add;
        offs[i] = o; cursor[i] = o;
    }
}

__global__ void k_scatter(const int* __restrict__ dst, const int* __restrict__ src,
                          int* __restrict__ cursor, int* __restrict__ esrc) {
    int e = blockIdx.x * 256 + threadIdx.x;
    if (e < NEDGES) {
        int d = dst[e];
        if ((unsigned)d < NNODES) {
            int p = atomicAdd(&cursor[d], 1);
            if ((unsigned)p < NEDGES) esrc[p] = src[e];
        }
    }
}

// ---------------- GEMM: C[M,N] tile 128(M) x BN(N); optional fused el/er epilogue ----------
// HEL > 0 requires BN == CH and grid.y == 1 (full row of C resident in the block).
template<int BN, bool ABF16, bool OUTF32, int HEL>
__global__ __launch_bounds__(256) void k_gemm(const void* __restrict__ Av,
                                              const unsigned short* __restrict__ BT,
                                              const float* __restrict__ bias,
                                              float* __restrict__ Cf,
                                              unsigned short* __restrict__ Cb,
                                              int M, int N,
                                              const float* __restrict__ al,
                                              const float* __restrict__ ar,
                                              float* __restrict__ el,
                                              float* __restrict__ er) {
    constexpr int BK  = 32;
    constexpr int NT  = BN / 16;
    constexpr int LDA = BK + 8;
    __shared__ unsigned short As[128][LDA];
    __shared__ unsigned short Bs[BN][LDA];
    const int t  = threadIdx.x;
    const int w  = t >> 6, l = t & 63;
    const int lm = l & 15, lk = (l >> 4) * 8;
    const int m0 = blockIdx.x * 128;
    const int n0 = blockIdx.y * BN;
    const float* Af = (const float*)Av;
    const unsigned short* Ab = (const unsigned short*)Av;

    floatx4 acc[2][NT];
#pragma unroll
    for (int mt = 0; mt < 2; ++mt)
#pragma unroll
        for (int nt = 0; nt < NT; ++nt) acc[mt][nt] = (floatx4)0.0f;

    for (int k0 = 0; k0 < 256; k0 += BK) {
        if (ABF16) {
#pragma unroll
            for (int p = 0; p < 2; ++p) {
                int chunk = t + p * 256;
                int r = chunk >> 2, cc = (chunk & 3) * 8;
                int row = m0 + r;
                uint4 val = make_uint4(0, 0, 0, 0);
                if (row < M) val = *(const uint4*)(Ab + (size_t)row * 256 + k0 + cc);
                *(uint4*)&As[r][cc] = val;
            }
        } else {
#pragma unroll
            for (int p = 0; p < 4; ++p) {
                int chunk = t + p * 256;
                int r = chunk >> 3, cc = (chunk & 7) * 4;
                int row = m0 + r;
                float4 v = make_float4(0.f, 0.f, 0.f, 0.f);
                if (row < M) v = *(const float4*)(Af + (size_t)row * 256 + k0 + cc);
                ushort4 o; o.x = f2bf(v.x); o.y = f2bf(v.y); o.z = f2bf(v.z); o.w = f2bf(v.w);
                *(ushort4*)&As[r][cc] = o;
            }
        }
#pragma unroll
        for (int p = 0; p < (BN * 4) / 256; ++p) {
            int chunk = t + p * 256;
            int r = chunk >> 2, cc = (chunk & 3) * 8;
            *(uint4*)&Bs[r][cc] = *(const uint4*)(BT + (size_t)(n0 + r) * 256 + k0 + cc);
        }
        __syncthreads();
        short8 af0 = *(const short8*)&As[w * 32 +      lm][lk];
        short8 af1 = *(const short8*)&As[w * 32 + 16 + lm][lk];
#pragma unroll
        for (int nt = 0; nt < NT; ++nt) {
            short8 bf = *(const short8*)&Bs[nt * 16 + lm][lk];
            acc[0][nt] = __builtin_amdgcn_mfma_f32_16x16x32_bf16(af0, bf, acc[0][nt], 0, 0, 0);
            acc[1][nt] = __builtin_amdgcn_mfma_f32_16x16x32_bf16(af1, bf, acc[1][nt], 0, 0, 0);
        }
        __syncthreads();
    }

    // attention-vector registers for fused el/er (loaded after K-loop: no loop pressure)
    float alv[HEL > 0 ? NT : 1], arv[HEL > 0 ? NT : 1];
    if (HEL > 0) {
#pragma unroll
        for (int nt = 0; nt < NT; ++nt) {
            alv[nt] = al[nt * 16 + lm];
            arv[nt] = ar[nt * 16 + lm];
        }
    }

#pragma unroll
    for (int mt = 0; mt < 2; ++mt)
#pragma unroll
        for (int j = 0; j < 4; ++j) {
            int row = m0 + w * 32 + mt * 16 + (l >> 4) * 4 + j;
            if (row < M) {
#pragma unroll
                for (int nt = 0; nt < NT; ++nt) {
                    int gcol = n0 + nt * 16 + lm;
                    float v = acc[mt][nt][j];
                    if (bias) v += bias[gcol];
                    if (OUTF32) Cf[(size_t)row * N + gcol] = v;
                    else        Cb[(size_t)row * N + gcol] = f2bf(v);
                }
                if (HEL > 0) {
                    // el[row,h] = sum_d ft[row, h*D+d] * al[h*D+d]; D = CH/HEL
                    // cols of head h are nt in [h*NT/HEL, (h+1)*NT/HEL)
#pragma unroll
                    for (int h = 0; h < HEL; ++h) {
                        float sl = 0.f, sr = 0.f;
#pragma unroll
                        for (int q = 0; q < NT / HEL; ++q) {
                            int nt = h * (NT / HEL) + q;
                            float v = acc[mt][nt][j];
                            sl += v * alv[nt];
                            sr += v * arv[nt];
                        }
                        // reduce across the 16 lm-lanes (they share this row)
#pragma unroll
                        for (int mm = 1; mm < 16; mm <<= 1) {
                            sl += __shfl_xor(sl, mm, 64);
                            sr += __shfl_xor(sr, mm, 64);
                        }
                        if (lm == 0) {
                            el[(size_t)row * HEL + h] = sl;
                            er[(size_t)row * HEL + h] = sr;
                        }
                    }
                }
            }
        }
}

// ---------------- aggregation: inline softmax weight + scalar (saddr) gather-FMA ----------
// One wave per dst node. Phase 1: lane = (slot,head) computes exp-weight inline.
// Phase 2: readlane-broadcast src (SGPR loads) + shfl-broadcast weight. No LDS.
template<int H, bool ELU, bool RESID>
__global__ __launch_bounds__(256) void k_agg3(
        const unsigned short* __restrict__ ft,
        const float* __restrict__ el, const float* __restrict__ er,
        const int* __restrict__ offs, const int* __restrict__ deg,
        const int* __restrict__ esrc,
        const unsigned short* __restrict__ resid16,
        const float* __restrict__ bias,
        unsigned short* __restrict__ out_bf,
        float* __restrict__ out_f) {
    int w = threadIdx.x >> 6;
    int n = blockIdx.x * 4 + w;
    int l = threadIdx.x & 63;
    int c = 4 * l;
    int st = __builtin_amdgcn_readfirstlane(offs[n]);
    int dg = __builtin_amdgcn_readfirstlane(deg[n]);
    if (st < 0 || dg < 0 || st > NEDGES || dg > NEDGES - st) dg = 0;
    float a0 = 0.f, a1 = 0.f, a2 = 0.f, a3 = 0.f, wsum = 0.f;
    const unsigned short* ftc = ft + c;

    if (H == 1) {
        float ern = er[n];
        for (int i = 0; i < dg; i += 64) {
            int idx = i + l;
            int sv = 0; float wv = 0.f;
            if (idx < dg) {
                sv = esrc[st + idx];
                float xv = el[sv] + ern;
                xv = (xv > 0.f) ? xv : 0.2f * xv;
                xv = fminf(xv, 60.f);
                wv = __expf(xv);
            }
            wsum += wv;
            int jmax = dg - i; if (jmax > 64) jmax = 64;
            int j = 0;
            for (; j + 4 <= jmax; j += 4) {
                int s0 = __builtin_amdgcn_readlane(sv, j + 0);
                int s1 = __builtin_amdgcn_readlane(sv, j + 1);
                int s2 = __builtin_amdgcn_readlane(sv, j + 2);
                int s3 = __builtin_amdgcn_readlane(sv, j + 3);
                float w0 = __int_as_float(__builtin_amdgcn_readlane(__float_as_int(wv), j + 0));
                float w1 = __int_as_float(__builtin_amdgcn_readlane(__float_as_int(wv), j + 1));
                float w2 = __int_as_float(__builtin_amdgcn_readlane(__float_as_int(wv), j + 2));
                float w3 = __int_as_float(__builtin_amdgcn_readlane(__float_as_int(wv), j + 3));
                ushort4 f0 = *(const ushort4*)(ftc + (size_t)s0 * CH);
                ushort4 f1 = *(const ushort4*)(ftc + (size_t)s1 * CH);
                ushort4 f2 = *(const ushort4*)(ftc + (size_t)s2 * CH);
                ushort4 f3 = *(const ushort4*)(ftc + (size_t)s3 * CH);
                a0 += w0 * bf2f(f0.x) + w1 * bf2f(f1.x) + w2 * bf2f(f2.x) + w3 * bf2f(f3.x);
                a1 += w0 * bf2f(f0.y) + w1 * bf2f(f1.y) + w2 * bf2f(f2.y) + w3 * bf2f(f3.y);
                a2 += w0 * bf2f(f0.z) + w1 * bf2f(f1.z) + w2 * bf2f(f2.z) + w3 * bf2f(f3.z);
                a3 += w0 * bf2f(f0.w) + w1 * bf2f(f1.w) + w2 * bf2f(f2.w) + w3 * bf2f(f3.w);
            }
            for (; j < jmax; ++j) {
                int s0 = __builtin_amdgcn_readlane(sv, j);
                float w0 = __int_as_float(__builtin_amdgcn_readlane(__float_as_int(wv), j));
                ushort4 f0 = *(const ushort4*)(ftc + (size_t)s0 * CH);
                a0 += w0 * bf2f(f0.x); a1 += w0 * bf2f(f0.y);
                a2 += w0 * bf2f(f0.z); a3 += w0 * bf2f(f0.w);
            }
        }
#pragma unroll
        for (int m = 1; m < 64; m <<= 1) wsum += __shfl_xor(wsum, m, 64);
    } else {
        int head = l & 3, slot = l >> 2;       // phase-1 role of this lane
        int h = l >> 4;                        // phase-2 head (c / 64)
        float ern = er[n * 4 + head];
        for (int i = 0; i < dg; i += 16) {
            int idx = i + slot;
            int sv = 0; float wv = 0.f;
            if (idx < dg) {
                sv = esrc[st + idx];
                float xv = el[sv * 4 + head] + ern;
                xv = (xv > 0.f) ? xv : 0.2f * xv;
                xv = fminf(xv, 60.f);
                wv = __expf(xv);
            }
            wsum += wv;
            int jmax = dg - i; if (jmax > 16) jmax = 16;
            int j = 0;
            for (; j + 4 <= jmax; j += 4) {
                int s0 = __builtin_amdgcn_readlane(sv, 4 * (j + 0));
                int s1 = __builtin_amdgcn_readlane(sv, 4 * (j + 1));
                int s2 = __builtin_amdgcn_readlane(sv, 4 * (j + 2));
                int s3 = __builtin_amdgcn_readlane(sv, 4 * (j + 3));
                float w0 = __shfl(wv, 4 * (j + 0) + h, 64);
                float w1 = __shfl(wv, 4 * (j + 1) + h, 64);
                float w2 = __shfl(wv, 4 * (j + 2) + h, 64);
                float w3 = __shfl(wv, 4 * (j + 3) + h, 64);
                ushort4 f0 = *(const ushort4*)(ftc + (size_t)s0 * CH);
                ushort4 f1 = *(const ushort4*)(ftc + (size_t)s1 * CH);
                ushort4 f2 = *(const ushort4*)(ftc + (size_t)s2 * CH);
                ushort4 f3 = *(const ushort4*)(ftc + (size_t)s3 * CH);
                a0 += w0 * bf2f(f0.x) + w1 * bf2f(f1.x) + w2 * bf2f(f2.x) + w3 * bf2f(f3.x);
                a1 += w0 * bf2f(f0.y) + w1 * bf2f(f1.y) + w2 * bf2f(f2.y) + w3 * bf2f(f3.y);
                a2 += w0 * bf2f(f0.z) + w1 * bf2f(f1.z) + w2 * bf2f(f2.z) + w3 * bf2f(f3.z);
                a3 += w0 * bf2f(f0.w) + w1 * bf2f(f1.w) + w2 * bf2f(f2.w) + w3 * bf2f(f3.w);
            }
            for (; j < jmax; ++j) {
                int s0 = __builtin_amdgcn_readlane(sv, 4 * j);
                float w0 = __shfl(wv, 4 * j + h, 64);
                ushort4 f0 = *(const ushort4*)(ftc + (size_t)s0 * CH);
                a0 += w0 * bf2f(f0.x); a1 += w0 * bf2f(f0.y);
                a2 += w0 * bf2f(f0.z); a3 += w0 * bf2f(f0.w);
            }
        }
        // per-head sum: reduce over slot bits, broadcast from lane matching phase-2 head
#pragma unroll
        for (int m = 4; m < 64; m <<= 1) wsum += __shfl_xor(wsum, m, 64);
        wsum = __shfl(wsum, h, 64);
    }
    float inv = (wsum > 1e-30f) ? 1.0f / wsum : 0.0f;
    a0 *= inv; a1 *= inv; a2 *= inv; a3 *= inv;
    if (RESID) {
        ushort4 r = *(const ushort4*)(resid16 + (size_t)n * CH + c);
        a0 += bf2f(r.x); a1 += bf2f(r.y); a2 += bf2f(r.z); a3 += bf2f(r.w);
    }
    {
        float4 b = *(const float4*)(bias + c);
        a0 += b.x; a1 += b.y; a2 += b.z; a3 += b.w;
    }
    if (ELU) {
        a0 = (a0 > 0.f) ? a0 : __expf(a0) - 1.f;
        a1 = (a1 > 0.f) ? a1 : __expf(a1) - 1.f;
        a2 = (a2 > 0.f) ? a2 : __expf(a2) - 1.f;
        a3 = (a3 > 0.f) ? a3 : __expf(a3) - 1.f;
    }
    if (out_bf) {
        ushort4 ov; ov.x = f2bf(a0); ov.y = f2bf(a1); ov.z = f2bf(a2); ov.w = f2bf(a3);
        *(ushort4*)(out_bf + (size_t)n * CH + c) = ov;
    }
    if (out_f) {
        *(float4*)(out_f + (size_t)n * CH + c) = make_float4(a0, a1, a2, a3);
    }
}

// ---------------- launch ----------------

extern "C" void kernel_launch(void* const* d_in, const int* in_sizes, int n_in,
                              void* d_out, int out_size, void* d_ws, size_t ws_size,
                              hipStream_t stream) {
    const float* x   = (const float*)d_in[0];
    const int*   src = (const int*)d_in[1];
    const int*   dst = (const int*)d_in[2];
    const float* W0  = (const float*)d_in[3];
    const float* al0 = (const float*)d_in[4];
    const float* ar0 = (const float*)d_in[5];
    const float* b0  = (const float*)d_in[6];
    const float* W1  = (const float*)d_in[7];
    const float* al1 = (const float*)d_in[8];
    const float* ar1 = (const float*)d_in[9];
    const float* b1  = (const float*)d_in[10];
    const float* Wl  = (const float*)d_in[11];
    const float* bl  = (const float*)d_in[12];

    float* out_logits = (float*)d_out;
    float* out_h      = out_logits + (size_t)NNODES * NCLS;

    // scratch in the logits region (12.8 MB; we use ~6.0 MB), overwritten last
    char* ob = (char*)d_out;
    size_t oo = 0;
    auto oalloc = [&](size_t b) { char* p = ob + oo; oo += (b + 255) & ~(size_t)255; return p; };
    int*   esrc = (int*)oalloc((size_t)NEDGES * 4);
    int*   deg  = (int*)oalloc((size_t)NNODES * 4);
    int*   offs = (int*)oalloc((size_t)NNODES * 4);
    int*   curs = (int*)oalloc((size_t)NNODES * 4);
    int*   scn  = (int*)oalloc((size_t)NNODES * 4);
    float* el0  = (float*)oalloc((size_t)NNODES * 4 * 4);
    float* er0  = (float*)oalloc((size_t)NNODES * 4 * 4);
    float* el1  = (float*)oalloc((size_t)NNODES * 4);
    float* er1  = (float*)oalloc((size_t)NNODES * 4);

    // ws: ft (25.6) + h0bf (25.6) + weights (~0.3) [+ h1bf (25.6) if room]
    char* ws = (char*)d_ws;
    size_t o = 0;
    auto alloc = [&](size_t b) { char* p = ws + o; o += (b + 255) & ~(size_t)255; return p; };
    unsigned short* ft   = (unsigned short*)alloc((size_t)NNODES * CH * 2);
    unsigned short* h0bf = (unsigned short*)alloc((size_t)NNODES * CH * 2);
    unsigned short* w0t  = (unsigned short*)alloc(256 * 256 * 2);
    unsigned short* w1t  = (unsigned short*)alloc(256 * 256 * 2);
    unsigned short* wlt  = (unsigned short*)alloc(64 * 256 * 2);
    int*            part = (int*)alloc(1024);
    int*            dmy  = (int*)alloc(256);
    unsigned short* h1bf = nullptr;
    if (o + (size_t)NNODES * CH * 2 <= ws_size) {
        h1bf = (unsigned short*)alloc((size_t)NNODES * CH * 2);
    }

    // ---- setup + CSR build ----
    k_setup<<<(147456 + NNODES + 255) / 256, 256, 0, stream>>>(W0, W1, Wl, w0t, w1t, wlt, deg);
    k_hist<<<(NEDGES + 255) / 256, 256, 0, stream>>>(dst, deg);
    int nb = (NNODES + 255) / 256;
    k_scan1<<<nb, 256, 0, stream>>>(deg, scn, part, NNODES);
    k_scan1<<<1, 256, 0, stream>>>(part, part, dmy, nb);
    k_scan3<<<nb, 256, 0, stream>>>(scn, deg, part, offs, curs, NNODES);
    k_scatter<<<(NEDGES + 255) / 256, 256, 0, stream>>>(dst, src, curs, esrc);

    int gm = (NNODES + 127) / 128;  // 391
    // ---- layer 0: GEMM (A read once, fused el/er epilogue) + agg ----
    k_gemm<256, false, false, 4><<<dim3(gm, 1), 256, 0, stream>>>(
        x, w0t, nullptr, nullptr, ft, NNODES, CH, al0, ar0, el0, er0);
    k_agg3<4, true, false><<<NNODES / 4, 256, 0, stream>>>(ft, el0, er0, offs, deg, esrc,
                                                           nullptr, b0, h0bf, nullptr);
    // ---- layer 1 ----
    k_gemm<256, true, false, 1><<<dim3(gm, 1), 256, 0, stream>>>(
        h0bf, w1t, nullptr, nullptr, ft, NNODES, CH, al1, ar1, el1, er1);
    k_agg3<1, false, true><<<NNODES / 4, 256, 0, stream>>>(ft, el1, er1, offs, deg, esrc,
                                                           h0bf, b1, h1bf, out_h);
    // ---- classifier ----
    if (h1bf) {
        k_gemm<64, true, true, 0><<<dim3(gm, 1), 256, 0, stream>>>(
            h1bf, wlt, bl, out_logits, nullptr, NNODES, NCLS,
            nullptr, nullptr, nullptr, nullptr);
    } else {
        k_gemm<64, false, true, 0><<<dim3(gm, 1), 256, 0, stream>>>(
            out_h, wlt, bl, out_logits, nullptr, NNODES, NCLS,
            nullptr, nullptr, nullptr, nullptr);
    }
}

// Round 3
// 393.740 us; speedup vs baseline: 1.1175x; 1.1175x over previous
//
#include <hip/hip_runtime.h>
#include <hip/hip_bf16.h>
#include <stdint.h>

#define NNODES 50000
#define NEDGES 800000
#define CH     256
#define NCLS   64

typedef __attribute__((ext_vector_type(8))) short  short8;
typedef __attribute__((ext_vector_type(4))) float  floatx4;

__device__ __forceinline__ float bf2f(unsigned short u) {
    union { unsigned int i; float f; } v; v.i = ((unsigned int)u) << 16; return v.f;
}
__device__ __forceinline__ unsigned short f2bf(float f) {
    union { float f; unsigned int i; } v; v.f = f;
    unsigned int x = v.i;
    return (unsigned short)((x + 0x7fffu + ((x >> 16) & 1u)) >> 16);  // RNE
}

// ---------------- fused setup: zero deg + transpose-convert all 3 weights ----------------
__global__ void k_setup(const float* __restrict__ W0, const float* __restrict__ W1,
                        const float* __restrict__ Wl,
                        unsigned short* __restrict__ w0t, unsigned short* __restrict__ w1t,
                        unsigned short* __restrict__ wlt, int* __restrict__ deg) {
    int i = blockIdx.x * 256 + threadIdx.x;
    if (i < 65536) {
        int r = i >> 8, c = i & 255;
        w0t[c * 256 + r] = f2bf(W0[i]);
    } else if (i < 131072) {
        int j = i - 65536;
        int r = j >> 8, c = j & 255;
        w1t[c * 256 + r] = f2bf(W1[j]);
    } else if (i < 147456) {
        int j = i - 131072;
        int r = j >> 6, c = j & 63;       // Wl is [256,64]
        wlt[c * 256 + r] = f2bf(Wl[j]);
    } else if (i < 147456 + NNODES) {
        deg[i - 147456] = 0;
    }
}

__global__ void k_hist(const int* __restrict__ dst, int* __restrict__ deg) {
    int e = blockIdx.x * 256 + threadIdx.x;
    if (e < NEDGES) {
        int d = dst[e];
        if ((unsigned)d < NNODES) atomicAdd(&deg[d], 1);
    }
}

__global__ void k_scan1(const int* __restrict__ in, int* __restrict__ out,
                        int* __restrict__ part, int n) {
    __shared__ int sm[256];
    int i = blockIdx.x * 256 + threadIdx.x;
    int v = (i < n) ? in[i] : 0;
    sm[threadIdx.x] = v;
    __syncthreads();
    for (int off = 1; off < 256; off <<= 1) {
        int t = (threadIdx.x >= (unsigned)off) ? sm[threadIdx.x - off] : 0;
        __syncthreads();
        sm[threadIdx.x] += t;
        __syncthreads();
    }
    if (i < n) out[i] = sm[threadIdx.x];
    if (threadIdx.x == 255) part[blockIdx.x] = sm[255];
}

__global__ void k_scan3(const int* __restrict__ scn, const int* __restrict__ deg,
                        const int* __restrict__ part, int* __restrict__ offs,
                        int* __restrict__ cursor, int n) {
    int i = blockIdx.x * 256 + threadIdx.x;
    if (i < n) {
        int add = (blockIdx.x > 0) ? part[blockIdx.x - 1] : 0;
        int o = scn[i] - deg[i] + add;
        offs[i] = o; cursor[i] = o;
    }
}

__global__ void k_scatter(const int* __restrict__ dst, const int* __restrict__ src,
                          int* __restrict__ cursor, int* __restrict__ esrc) {
    int e = blockIdx.x * 256 + threadIdx.x;
    if (e < NEDGES) {
        int d = dst[e];
        if ((unsigned)d < NNODES) {
            int p = atomicAdd(&cursor[d], 1);
            if ((unsigned)p < NEDGES) esrc[p] = src[e];
        }
    }
}

// ---------------- GEMM: C[M,N], tile 64(M) x BN(N), double-buffered 2-phase pipeline ------
// grid.x = ceil(M/64); BN == N (full row resident). HEL>0 fuses el/er epilogue.
template<int BN, bool ABF16, bool OUTF32, int HEL>
__global__ __launch_bounds__(256) void k_gemm64(const void* __restrict__ Av,
                                                const unsigned short* __restrict__ BT,
                                                const float* __restrict__ bias,
                                                float* __restrict__ Cf,
                                                unsigned short* __restrict__ Cb,
                                                int M, int N,
                                                const float* __restrict__ al,
                                                const float* __restrict__ ar,
                                                float* __restrict__ el,
                                                float* __restrict__ er) {
    constexpr int BK  = 32;
    constexpr int NT  = BN / 16;
    constexpr int LDA = BK + 8;
    constexpr int BNV = (BN * 4) / 256;   // uint4 per thread for B staging
    __shared__ unsigned short As[2][64][LDA];
    __shared__ unsigned short Bs[2][BN][LDA];
    const int t  = threadIdx.x;
    const int w  = t >> 6, l = t & 63;
    const int lm = l & 15, lk = (l >> 4) * 8;
    const int m0 = blockIdx.x * 64;
    const float* Af = (const float*)Av;
    const unsigned short* Ab = (const unsigned short*)Av;

    // staging index precompute
    const int ar16 = t >> 2, ac16 = (t & 3) * 8;      // bf16 A: 1 chunk/thread

    floatx4 acc[NT];
#pragma unroll
    for (int nt = 0; nt < NT; ++nt) acc[nt] = (floatx4)0.0f;

    // ---- prologue: stage k0=0 into buffer 0 ----
    {
        if (ABF16) {
            int row = m0 + ar16;
            uint4 v = make_uint4(0, 0, 0, 0);
            if (row < M) v = *(const uint4*)(Ab + (size_t)row * 256 + 0 + ac16);
            *(uint4*)&As[0][ar16][ac16] = v;
        } else {
#pragma unroll
            for (int p = 0; p < 2; ++p) {
                int chunk = t + p * 256;
                int r = chunk >> 3, cc = (chunk & 7) * 4;
                int row = m0 + r;
                float4 v = make_float4(0.f, 0.f, 0.f, 0.f);
                if (row < M) v = *(const float4*)(Af + (size_t)row * 256 + 0 + cc);
                ushort4 o; o.x = f2bf(v.x); o.y = f2bf(v.y); o.z = f2bf(v.z); o.w = f2bf(v.w);
                *(ushort4*)&As[0][r][cc] = o;
            }
        }
#pragma unroll
        for (int p = 0; p < BNV; ++p) {
            int chunk = t + p * 256;
            int r = chunk >> 2, cc = (chunk & 3) * 8;
            *(uint4*)&Bs[0][r][cc] = *(const uint4*)(BT + (size_t)r * 256 + 0 + cc);
        }
    }
    __syncthreads();

    int cur = 0;
    for (int ks = 1; ks < 8; ++ks) {
        int k0 = ks * BK;
        // ---- issue next-tile global loads into registers ----
        uint4  rau;
        float4 raf[2];
        uint4  rb[BNV];
        if (ABF16) {
            int row = m0 + ar16;
            rau = make_uint4(0, 0, 0, 0);
            if (row < M) rau = *(const uint4*)(Ab + (size_t)row * 256 + k0 + ac16);
        } else {
#pragma unroll
            for (int p = 0; p < 2; ++p) {
                int chunk = t + p * 256;
                int r = chunk >> 3, cc = (chunk & 7) * 4;
                int row = m0 + r;
                raf[p] = make_float4(0.f, 0.f, 0.f, 0.f);
                if (row < M) raf[p] = *(const float4*)(Af + (size_t)row * 256 + k0 + cc);
            }
        }
#pragma unroll
        for (int p = 0; p < BNV; ++p) {
            int chunk = t + p * 256;
            int r = chunk >> 2, cc = (chunk & 3) * 8;
            rb[p] = *(const uint4*)(BT + (size_t)r * 256 + k0 + cc);
        }
        // ---- compute current buffer ----
        {
            short8 af = *(const short8*)&As[cur][w * 16 + lm][lk];
#pragma unroll
            for (int nt = 0; nt < NT; ++nt) {
                short8 bf = *(const short8*)&Bs[cur][nt * 16 + lm][lk];
                acc[nt] = __builtin_amdgcn_mfma_f32_16x16x32_bf16(af, bf, acc[nt], 0, 0, 0);
            }
        }
        // ---- write staged regs to alternate buffer ----
        int nxt = cur ^ 1;
        if (ABF16) {
            *(uint4*)&As[nxt][ar16][ac16] = rau;
        } else {
#pragma unroll
            for (int p = 0; p < 2; ++p) {
                int chunk = t + p * 256;
                int r = chunk >> 3, cc = (chunk & 7) * 4;
                ushort4 o; o.x = f2bf(raf[p].x); o.y = f2bf(raf[p].y);
                o.z = f2bf(raf[p].z); o.w = f2bf(raf[p].w);
                *(ushort4*)&As[nxt][r][cc] = o;
            }
        }
#pragma unroll
        for (int p = 0; p < BNV; ++p) {
            int chunk = t + p * 256;
            int r = chunk >> 2, cc = (chunk & 3) * 8;
            *(uint4*)&Bs[nxt][r][cc] = rb[p];
        }
        __syncthreads();
        cur = nxt;
    }
    // ---- final K-step compute ----
    {
        short8 af = *(const short8*)&As[cur][w * 16 + lm][lk];
#pragma unroll
        for (int nt = 0; nt < NT; ++nt) {
            short8 bf = *(const short8*)&Bs[cur][nt * 16 + lm][lk];
            acc[nt] = __builtin_amdgcn_mfma_f32_16x16x32_bf16(af, bf, acc[nt], 0, 0, 0);
        }
    }

    // attention vectors for fused el/er
    float alv[HEL > 0 ? NT : 1], arv[HEL > 0 ? NT : 1];
    if (HEL > 0) {
#pragma unroll
        for (int nt = 0; nt < NT; ++nt) {
            alv[nt] = al[nt * 16 + lm];
            arv[nt] = ar[nt * 16 + lm];
        }
    }

#pragma unroll
    for (int j = 0; j < 4; ++j) {
        int row = m0 + w * 16 + (l >> 4) * 4 + j;
        if (row < M) {
#pragma unroll
            for (int nt = 0; nt < NT; ++nt) {
                int gcol = nt * 16 + lm;
                float v = acc[nt][j];
                if (bias) v += bias[gcol];
                if (OUTF32) Cf[(size_t)row * N + gcol] = v;
                else        Cb[(size_t)row * N + gcol] = f2bf(v);
            }
            if (HEL > 0) {
#pragma unroll
                for (int h = 0; h < HEL; ++h) {
                    float sl = 0.f, sr = 0.f;
#pragma unroll
                    for (int q = 0; q < NT / HEL; ++q) {
                        int nt = h * (NT / HEL) + q;
                        float v = acc[nt][j];
                        sl += v * alv[nt];
                        sr += v * arv[nt];
                    }
#pragma unroll
                    for (int mm = 1; mm < 16; mm <<= 1) {
                        sl += __shfl_xor(sl, mm, 64);
                        sr += __shfl_xor(sr, mm, 64);
                    }
                    if (lm == 0) {
                        el[(size_t)row * HEL + h] = sl;
                        er[(size_t)row * HEL + h] = sr;
                    }
                }
            }
        }
    }
}

// ---------------- aggregation: inline softmax weight + scalar (saddr) gather-FMA ----------
template<int H, bool ELU, bool RESID>
__global__ __launch_bounds__(256) void k_agg3(
        const unsigned short* __restrict__ ft,
        const float* __restrict__ el, const float* __restrict__ er,
        const int* __restrict__ offs, const int* __restrict__ deg,
        const int* __restrict__ esrc,
        const unsigned short* __restrict__ resid16,
        const float* __restrict__ bias,
        unsigned short* __restrict__ out_bf,
        float* __restrict__ out_f) {
    int w = threadIdx.x >> 6;
    int n = blockIdx.x * 4 + w;
    int l = threadIdx.x & 63;
    int c = 4 * l;
    int st = __builtin_amdgcn_readfirstlane(offs[n]);
    int dg = __builtin_amdgcn_readfirstlane(deg[n]);
    if (st < 0 || dg < 0 || st > NEDGES || dg > NEDGES - st) dg = 0;
    float a0 = 0.f, a1 = 0.f, a2 = 0.f, a3 = 0.f, wsum = 0.f;
    const unsigned short* ftc = ft + c;

    if (H == 1) {
        float ern = er[n];
        for (int i = 0; i < dg; i += 64) {
            int idx = i + l;
            int sv = 0; float wv = 0.f;
            if (idx < dg) {
                sv = esrc[st + idx];
                float xv = el[sv] + ern;
                xv = (xv > 0.f) ? xv : 0.2f * xv;
                xv = fminf(xv, 60.f);
                wv = __expf(xv);
            }
            wsum += wv;
            int jmax = dg - i; if (jmax > 64) jmax = 64;
            int j = 0;
            for (; j + 4 <= jmax; j += 4) {
                int s0 = __builtin_amdgcn_readlane(sv, j + 0);
                int s1 = __builtin_amdgcn_readlane(sv, j + 1);
                int s2 = __builtin_amdgcn_readlane(sv, j + 2);
                int s3 = __builtin_amdgcn_readlane(sv, j + 3);
                float w0 = __int_as_float(__builtin_amdgcn_readlane(__float_as_int(wv), j + 0));
                float w1 = __int_as_float(__builtin_amdgcn_readlane(__float_as_int(wv), j + 1));
                float w2 = __int_as_float(__builtin_amdgcn_readlane(__float_as_int(wv), j + 2));
                float w3 = __int_as_float(__builtin_amdgcn_readlane(__float_as_int(wv), j + 3));
                ushort4 f0 = *(const ushort4*)(ftc + (size_t)s0 * CH);
                ushort4 f1 = *(const ushort4*)(ftc + (size_t)s1 * CH);
                ushort4 f2 = *(const ushort4*)(ftc + (size_t)s2 * CH);
                ushort4 f3 = *(const ushort4*)(ftc + (size_t)s3 * CH);
                a0 += w0 * bf2f(f0.x) + w1 * bf2f(f1.x) + w2 * bf2f(f2.x) + w3 * bf2f(f3.x);
                a1 += w0 * bf2f(f0.y) + w1 * bf2f(f1.y) + w2 * bf2f(f2.y) + w3 * bf2f(f3.y);
                a2 += w0 * bf2f(f0.z) + w1 * bf2f(f1.z) + w2 * bf2f(f2.z) + w3 * bf2f(f3.z);
                a3 += w0 * bf2f(f0.w) + w1 * bf2f(f1.w) + w2 * bf2f(f2.w) + w3 * bf2f(f3.w);
            }
            for (; j < jmax; ++j) {
                int s0 = __builtin_amdgcn_readlane(sv, j);
                float w0 = __int_as_float(__builtin_amdgcn_readlane(__float_as_int(wv), j));
                ushort4 f0 = *(const ushort4*)(ftc + (size_t)s0 * CH);
                a0 += w0 * bf2f(f0.x); a1 += w0 * bf2f(f0.y);
                a2 += w0 * bf2f(f0.z); a3 += w0 * bf2f(f0.w);
            }
        }
#pragma unroll
        for (int m = 1; m < 64; m <<= 1) wsum += __shfl_xor(wsum, m, 64);
    } else {
        int head = l & 3, slot = l >> 2;       // phase-1 role of this lane
        int h = l >> 4;                        // phase-2 head (c / 64)
        float ern = er[n * 4 + head];
        for (int i = 0; i < dg; i += 16) {
            int idx = i + slot;
            int sv = 0; float wv = 0.f;
            if (idx < dg) {
                sv = esrc[st + idx];
                float xv = el[sv * 4 + head] + ern;
                xv = (xv > 0.f) ? xv : 0.2f * xv;
                xv = fminf(xv, 60.f);
                wv = __expf(xv);
            }
            wsum += wv;
            int jmax = dg - i; if (jmax > 16) jmax = 16;
            int j = 0;
            for (; j + 4 <= jmax; j += 4) {
                int s0 = __builtin_amdgcn_readlane(sv, 4 * (j + 0));
                int s1 = __builtin_amdgcn_readlane(sv, 4 * (j + 1));
                int s2 = __builtin_amdgcn_readlane(sv, 4 * (j + 2));
                int s3 = __builtin_amdgcn_readlane(sv, 4 * (j + 3));
                float w0 = __shfl(wv, 4 * (j + 0) + h, 64);
                float w1 = __shfl(wv, 4 * (j + 1) + h, 64);
                float w2 = __shfl(wv, 4 * (j + 2) + h, 64);
                float w3 = __shfl(wv, 4 * (j + 3) + h, 64);
                ushort4 f0 = *(const ushort4*)(ftc + (size_t)s0 * CH);
                ushort4 f1 = *(const ushort4*)(ftc + (size_t)s1 * CH);
                ushort4 f2 = *(const ushort4*)(ftc + (size_t)s2 * CH);
                ushort4 f3 = *(const ushort4*)(ftc + (size_t)s3 * CH);
                a0 += w0 * bf2f(f0.x) + w1 * bf2f(f1.x) + w2 * bf2f(f2.x) + w3 * bf2f(f3.x);
                a1 += w0 * bf2f(f0.y) + w1 * bf2f(f1.y) + w2 * bf2f(f2.y) + w3 * bf2f(f3.y);
                a2 += w0 * bf2f(f0.z) + w1 * bf2f(f1.z) + w2 * bf2f(f2.z) + w3 * bf2f(f3.z);
                a3 += w0 * bf2f(f0.w) + w1 * bf2f(f1.w) + w2 * bf2f(f2.w) + w3 * bf2f(f3.w);
            }
            for (; j < jmax; ++j) {
                int s0 = __builtin_amdgcn_readlane(sv, 4 * j);
                float w0 = __shfl(wv, 4 * j + h, 64);
                ushort4 f0 = *(const ushort4*)(ftc + (size_t)s0 * CH);
                a0 += w0 * bf2f(f0.x); a1 += w0 * bf2f(f0.y);
                a2 += w0 * bf2f(f0.z); a3 += w0 * bf2f(f0.w);
            }
        }
#pragma unroll
        for (int m = 4; m < 64; m <<= 1) wsum += __shfl_xor(wsum, m, 64);
        wsum = __shfl(wsum, h, 64);
    }
    float inv = (wsum > 1e-30f) ? 1.0f / wsum : 0.0f;
    a0 *= inv; a1 *= inv; a2 *= inv; a3 *= inv;
    if (RESID) {
        ushort4 r = *(const ushort4*)(resid16 + (size_t)n * CH + c);
        a0 += bf2f(r.x); a1 += bf2f(r.y); a2 += bf2f(r.z); a3 += bf2f(r.w);
    }
    {
        float4 b = *(const float4*)(bias + c);
        a0 += b.x; a1 += b.y; a2 += b.z; a3 += b.w;
    }
    if (ELU) {
        a0 = (a0 > 0.f) ? a0 : __expf(a0) - 1.f;
        a1 = (a1 > 0.f) ? a1 : __expf(a1) - 1.f;
        a2 = (a2 > 0.f) ? a2 : __expf(a2) - 1.f;
        a3 = (a3 > 0.f) ? a3 : __expf(a3) - 1.f;
    }
    if (out_bf) {
        ushort4 ov; ov.x = f2bf(a0); ov.y = f2bf(a1); ov.z = f2bf(a2); ov.w = f2bf(a3);
        *(ushort4*)(out_bf + (size_t)n * CH + c) = ov;
    }
    if (out_f) {
        *(float4*)(out_f + (size_t)n * CH + c) = make_float4(a0, a1, a2, a3);
    }
}

// ---------------- launch ----------------

extern "C" void kernel_launch(void* const* d_in, const int* in_sizes, int n_in,
                              void* d_out, int out_size, void* d_ws, size_t ws_size,
                              hipStream_t stream) {
    const float* x   = (const float*)d_in[0];
    const int*   src = (const int*)d_in[1];
    const int*   dst = (const int*)d_in[2];
    const float* W0  = (const float*)d_in[3];
    const float* al0 = (const float*)d_in[4];
    const float* ar0 = (const float*)d_in[5];
    const float* b0  = (const float*)d_in[6];
    const float* W1  = (const float*)d_in[7];
    const float* al1 = (const float*)d_in[8];
    const float* ar1 = (const float*)d_in[9];
    const float* b1  = (const float*)d_in[10];
    const float* Wl  = (const float*)d_in[11];
    const float* bl  = (const float*)d_in[12];

    float* out_logits = (float*)d_out;
    float* out_h      = out_logits + (size_t)NNODES * NCLS;

    // scratch in the logits region (12.8 MB; we use ~6.0 MB), overwritten last
    char* ob = (char*)d_out;
    size_t oo = 0;
    auto oalloc = [&](size_t b) { char* p = ob + oo; oo += (b + 255) & ~(size_t)255; return p; };
    int*   esrc = (int*)oalloc((size_t)NEDGES * 4);
    int*   deg  = (int*)oalloc((size_t)NNODES * 4);
    int*   offs = (int*)oalloc((size_t)NNODES * 4);
    int*   curs = (int*)oalloc((size_t)NNODES * 4);
    int*   scn  = (int*)oalloc((size_t)NNODES * 4);
    float* el0  = (float*)oalloc((size_t)NNODES * 4 * 4);
    float* er0  = (float*)oalloc((size_t)NNODES * 4 * 4);
    float* el1  = (float*)oalloc((size_t)NNODES * 4);
    float* er1  = (float*)oalloc((size_t)NNODES * 4);

    // ws: ft (25.6) + h0bf (25.6) + weights (~0.3) [+ h1bf (25.6) if room]
    char* ws = (char*)d_ws;
    size_t o = 0;
    auto alloc = [&](size_t b) { char* p = ws + o; o += (b + 255) & ~(size_t)255; return p; };
    unsigned short* ft   = (unsigned short*)alloc((size_t)NNODES * CH * 2);
    unsigned short* h0bf = (unsigned short*)alloc((size_t)NNODES * CH * 2);
    unsigned short* w0t  = (unsigned short*)alloc(256 * 256 * 2);
    unsigned short* w1t  = (unsigned short*)alloc(256 * 256 * 2);
    unsigned short* wlt  = (unsigned short*)alloc(64 * 256 * 2);
    int*            part = (int*)alloc(1024);
    int*            dmy  = (int*)alloc(256);
    unsigned short* h1bf = nullptr;
    if (o + (size_t)NNODES * CH * 2 <= ws_size) {
        h1bf = (unsigned short*)alloc((size_t)NNODES * CH * 2);
    }

    // ---- setup + CSR build ----
    k_setup<<<(147456 + NNODES + 255) / 256, 256, 0, stream>>>(W0, W1, Wl, w0t, w1t, wlt, deg);
    k_hist<<<(NEDGES + 255) / 256, 256, 0, stream>>>(dst, deg);
    int nb = (NNODES + 255) / 256;
    k_scan1<<<nb, 256, 0, stream>>>(deg, scn, part, NNODES);
    k_scan1<<<1, 256, 0, stream>>>(part, part, dmy, nb);
    k_scan3<<<nb, 256, 0, stream>>>(scn, deg, part, offs, curs, NNODES);
    k_scatter<<<(NEDGES + 255) / 256, 256, 0, stream>>>(dst, src, curs, esrc);

    int gm = (NNODES + 63) / 64;  // 782
    // ---- layer 0: GEMM (A read once, fused el/er) + agg ----
    k_gemm64<256, false, false, 4><<<gm, 256, 0, stream>>>(
        x, w0t, nullptr, nullptr, ft, NNODES, CH, al0, ar0, el0, er0);
    k_agg3<4, true, false><<<NNODES / 4, 256, 0, stream>>>(ft, el0, er0, offs, deg, esrc,
                                                           nullptr, b0, h0bf, nullptr);
    // ---- layer 1 ----
    k_gemm64<256, true, false, 1><<<gm, 256, 0, stream>>>(
        h0bf, w1t, nullptr, nullptr, ft, NNODES, CH, al1, ar1, el1, er1);
    k_agg3<1, false, true><<<NNODES / 4, 256, 0, stream>>>(ft, el1, er1, offs, deg, esrc,
                                                           h0bf, b1, h1bf, out_h);
    // ---- classifier ----
    if (h1bf) {
        k_gemm64<64, true, true, 0><<<gm, 256, 0, stream>>>(
            h1bf, wlt, bl, out_logits, nullptr, NNODES, NCLS,
            nullptr, nullptr, nullptr, nullptr);
    } else {
        k_gemm64<64, false, true, 0><<<gm, 256, 0, stream>>>(
            out_h, wlt, bl, out_logits, nullptr, NNODES, NCLS,
            nullptr, nullptr, nullptr, nullptr);
    }
}